// Round 4
// baseline (35.874 us; speedup 1.0000x reference)
//
#include <hip/hip_runtime.h>

// Dynamic 3x3 softmax-weighted conv, reflect padding.
// x: (4, 64, 256, 256) f32, kernel: (4, 9, 256, 256) f32, out: (4, 64, 256, 256) f32

constexpr int BATCH = 4;
constexpr int CHAN  = 64;
constexpr int HH    = 256;
constexpr int WW    = 256;
constexpr int CG    = 16;  // channels per block
constexpr int RPB   = 4;   // rows per block (one wave per row)

__global__ __launch_bounds__(256, 4) void dynconv_kernel(
    const float* __restrict__ x,
    const float* __restrict__ ker,
    float* __restrict__ out)
{
    const int t  = threadIdx.x;
    const int rb = t >> 6;          // wave id = row in band, 0..3
    const int wq = t & 63;          // lane = float4 slot
    const int w0 = wq * 4;

    const int hband = blockIdx.x;   // 0..63
    const int cg    = blockIdx.y;   // 0..3
    const int b     = blockIdx.z;   // 0..3
    const int h     = hband * RPB + rb;

    // ---- softmax over the 9 taps for this thread's 4 pixels ----
    float kv[9][4];
    const long kbase = (((long)b * 9) * HH + h) * WW + w0;
    #pragma unroll
    for (int j = 0; j < 9; ++j) {
        const float4 v = *reinterpret_cast<const float4*>(ker + kbase + (long)j * HH * WW);
        kv[j][0] = v.x; kv[j][1] = v.y; kv[j][2] = v.z; kv[j][3] = v.w;
    }
    #pragma unroll
    for (int p = 0; p < 4; ++p) {
        float m = kv[0][p];
        #pragma unroll
        for (int j = 1; j < 9; ++j) m = fmaxf(m, kv[j][p]);
        float s = 0.f;
        #pragma unroll
        for (int j = 0; j < 9; ++j) { kv[j][p] = __expf(kv[j][p] - m); s += kv[j][p]; }
        const float inv = 1.0f / s;
        #pragma unroll
        for (int j = 0; j < 9; ++j) kv[j][p] *= inv;
    }

    // ---- reflect row indices ----
    const int hm = (h == 0)      ? 1      : h - 1;
    const int hp = (h == HH - 1) ? HH - 2 : h + 1;

    const long cs    = (long)HH * WW;                 // channel stride
    const long roff0 = (long)hm * WW + w0;
    const long roff1 = (long)h  * WW + w0;
    const long roff2 = (long)hp * WW + w0;
    const long ooff  = (long)h  * WW + w0;

    const float* xb = x   + (((long)b * CHAN + cg * CG) * cs);
    float*       ob = out + (((long)b * CHAN + cg * CG) * cs);

#define LOADR(dst, ci) do {                                                   \
    dst[0] = *reinterpret_cast<const float4*>(xb + (long)(ci) * cs + roff0);  \
    dst[1] = *reinterpret_cast<const float4*>(xb + (long)(ci) * cs + roff1);  \
    dst[2] = *reinterpret_cast<const float4*>(xb + (long)(ci) * cs + roff2);  \
} while (0)

#define COMPUTE(ci, rr) do {                                                  \
    float a0 = 0.f, a1 = 0.f, a2 = 0.f, a3 = 0.f;                             \
    _Pragma("unroll")                                                         \
    for (int r = 0; r < 3; ++r) {                                             \
        const float4 v = rr[r];                                               \
        float lft = __shfl_up(v.w, 1);   if (wq == 0)  lft = v.y;             \
        float rgt = __shfl_down(v.x, 1); if (wq == 63) rgt = v.z;             \
        const float vals[6] = { lft, v.x, v.y, v.z, v.w, rgt };               \
        _Pragma("unroll")                                                     \
        for (int dx = 0; dx < 3; ++dx) {                                      \
            const int j = r * 3 + dx;                                         \
            a0 = fmaf(kv[j][0], vals[0 + dx], a0);                            \
            a1 = fmaf(kv[j][1], vals[1 + dx], a1);                            \
            a2 = fmaf(kv[j][2], vals[2 + dx], a2);                            \
            a3 = fmaf(kv[j][3], vals[3 + dx], a3);                            \
        }                                                                     \
    }                                                                         \
    float4 o; o.x = a0; o.y = a1; o.z = a2; o.w = a3;                         \
    *reinterpret_cast<float4*>(ob + (long)(ci) * cs + ooff) = o;              \
} while (0)

    // depth-2x2 software pipeline over the CG channels
    float4 rA[3], rB[3];
    LOADR(rA, 0);
    LOADR(rB, 1);
    #pragma unroll 1
    for (int i = 0; i < CG; i += 2) {
        float4 nA[3], nB[3];
        const bool more = (i + 2 < CG);
        if (more) { LOADR(nA, i + 2); LOADR(nB, i + 3); }
        COMPUTE(i,     rA);
        COMPUTE(i + 1, rB);
        if (more) {
            #pragma unroll
            for (int r = 0; r < 3; ++r) { rA[r] = nA[r]; rB[r] = nB[r]; }
        }
    }
#undef LOADR
#undef COMPUTE
}

extern "C" void kernel_launch(void* const* d_in, const int* in_sizes, int n_in,
                              void* d_out, int out_size, void* d_ws, size_t ws_size,
                              hipStream_t stream) {
    const float* x   = (const float*)d_in[0];
    const float* ker = (const float*)d_in[1];
    float* out = (float*)d_out;

    dim3 grid(HH / RPB, CHAN / CG, BATCH);  // (64, 4, 4)
    dim3 block(256);
    dynconv_kernel<<<grid, block, 0, stream>>>(x, ker, out);
}

// Round 6
// 32.054 us; speedup vs baseline: 1.1192x; 1.1192x over previous
//
#include <hip/hip_runtime.h>

// Dynamic 3x3 softmax-weighted conv, reflect padding.
// x: (4, 64, 256, 256) f32, kernel: (4, 9, 256, 256) f32, out: (4, 64, 256, 256) f32

constexpr int BATCH = 4;
constexpr int CHAN  = 64;
constexpr int HH    = 256;
constexpr int WW    = 256;
constexpr int CG    = 4;   // channels per block (small -> many blocks -> TLP)
constexpr int RPB   = 4;   // rows per block (one wave per row)

typedef float vf4 __attribute__((ext_vector_type(4)));

__global__ __launch_bounds__(256) void dynconv_kernel(
    const float* __restrict__ x,
    const float* __restrict__ ker,
    float* __restrict__ out)
{
    const int t  = threadIdx.x;
    const int rb = t >> 6;          // wave id = row in band, 0..3
    const int wq = t & 63;          // lane = float4 slot
    const int w0 = wq * 4;

    const int hband = blockIdx.x;   // 0..63
    const int cg    = blockIdx.y;   // 0..15
    const int b     = blockIdx.z;   // 0..3
    const int h     = hband * RPB + rb;

    // ---- softmax over the 9 taps for this thread's 4 pixels ----
    float kv[9][4];
    const long kbase = (((long)b * 9) * HH + h) * WW + w0;
    #pragma unroll
    for (int j = 0; j < 9; ++j) {
        const float4 v = *reinterpret_cast<const float4*>(ker + kbase + (long)j * HH * WW);
        kv[j][0] = v.x; kv[j][1] = v.y; kv[j][2] = v.z; kv[j][3] = v.w;
    }
    #pragma unroll
    for (int p = 0; p < 4; ++p) {
        float m = kv[0][p];
        #pragma unroll
        for (int j = 1; j < 9; ++j) m = fmaxf(m, kv[j][p]);
        float s = 0.f;
        #pragma unroll
        for (int j = 0; j < 9; ++j) { kv[j][p] = __expf(kv[j][p] - m); s += kv[j][p]; }
        const float inv = 1.0f / s;
        #pragma unroll
        for (int j = 0; j < 9; ++j) kv[j][p] *= inv;
    }

    // ---- reflect row indices (pad=1, 'reflect': -1 -> 1, N -> N-2) ----
    const int hm = (h == 0)      ? 1      : h - 1;
    const int hp = (h == HH - 1) ? HH - 2 : h + 1;
    const int rows[3] = { hm, h, hp };

    const long cs = (long)HH * WW;  // channel stride
    const float* xb = x   + (((long)b * CHAN + cg * CG) * cs);
    float*       ob = out + (((long)b * CHAN + cg * CG) * cs);

    // ---- fully unrolled over CG channels; halo via cross-lane shuffle ----
    #pragma unroll
    for (int i = 0; i < CG; ++i) {
        float acc0 = 0.f, acc1 = 0.f, acc2 = 0.f, acc3 = 0.f;
        #pragma unroll
        for (int r = 0; r < 3; ++r) {
            const long rbase = (long)i * cs + (long)rows[r] * WW;
            const float4 v = *reinterpret_cast<const float4*>(xb + rbase + w0);
            // left halo: lane-1's v.w; lane 0 reflects x[-1] -> x[1] = own v.y
            float lft = __shfl_up(v.w, 1);
            if (wq == 0)  lft = v.y;
            // right halo: lane+1's v.x; lane 63 reflects x[256] -> x[254] = own v.z
            float rgt = __shfl_down(v.x, 1);
            if (wq == 63) rgt = v.z;
            const float vals[6] = { lft, v.x, v.y, v.z, v.w, rgt };
            #pragma unroll
            for (int dx = 0; dx < 3; ++dx) {
                const int j = r * 3 + dx;
                acc0 = fmaf(kv[j][0], vals[0 + dx], acc0);
                acc1 = fmaf(kv[j][1], vals[1 + dx], acc1);
                acc2 = fmaf(kv[j][2], vals[2 + dx], acc2);
                acc3 = fmaf(kv[j][3], vals[3 + dx], acc3);
            }
        }
        vf4 o; o.x = acc0; o.y = acc1; o.z = acc2; o.w = acc3;
        __builtin_nontemporal_store(o, reinterpret_cast<vf4*>(ob + (long)i * cs + (long)h * WW + w0));
    }
}

extern "C" void kernel_launch(void* const* d_in, const int* in_sizes, int n_in,
                              void* d_out, int out_size, void* d_ws, size_t ws_size,
                              hipStream_t stream) {
    const float* x   = (const float*)d_in[0];
    const float* ker = (const float*)d_in[1];
    float* out = (float*)d_out;

    dim3 grid(HH / RPB, CHAN / CG, BATCH);  // (64, 16, 4)
    dim3 block(256);
    dynconv_kernel<<<grid, block, 0, stream>>>(x, ker, out);
}

// Round 7
// 31.123 us; speedup vs baseline: 1.1526x; 1.0299x over previous
//
#include <hip/hip_runtime.h>

// Dynamic 3x3 softmax-weighted conv, reflect padding.
// x: (4, 64, 256, 256) f32, kernel: (4, 9, 256, 256) f32, out: (4, 64, 256, 256) f32

constexpr int BATCH = 4;
constexpr int CHAN  = 64;
constexpr int HH    = 256;
constexpr int WW    = 256;
constexpr int CG    = 4;   // channels per block
constexpr int RPB   = 4;   // rows per block (one wave per row)

typedef float vf4 __attribute__((ext_vector_type(4)));

__global__ __launch_bounds__(256) void dynconv_kernel(
    const float* __restrict__ x,
    const float* __restrict__ ker,
    float* __restrict__ out)
{
    const int t  = threadIdx.x;
    const int rb = t >> 6;          // wave id = row in band, 0..3
    const int wq = t & 63;          // lane = float4 slot
    const int w0 = wq * 4;

    const int hband = blockIdx.x;   // 0..63
    const int cg    = blockIdx.y;   // 0..15
    const int b     = blockIdx.z;   // 0..3
    const int h     = hband * RPB + rb;

    // ---- reflect row indices (pad=1, 'reflect': -1 -> 1, N -> N-2) ----
    const int hm = (h == 0)      ? 1      : h - 1;
    const int hp = (h == HH - 1) ? HH - 2 : h + 1;

    const long cs = (long)HH * WW;  // channel stride
    const float* xb = x   + (((long)b * CHAN + cg * CG) * cs);
    float*       ob = out + (((long)b * CHAN + cg * CG) * cs);
    const long roff[3] = { (long)hm * WW + w0, (long)h * WW + w0, (long)hp * WW + w0 };

    // ---- issue ALL loads up front: 9 ker + 12 x float4s ----
    const long kbase = (((long)b * 9) * HH + h) * WW + w0;
    float kv[9][4];
    #pragma unroll
    for (int j = 0; j < 9; ++j) {
        const float4 v = *reinterpret_cast<const float4*>(ker + kbase + (long)j * HH * WW);
        kv[j][0] = v.x; kv[j][1] = v.y; kv[j][2] = v.z; kv[j][3] = v.w;
    }
    float4 xr[CG][3];
    #pragma unroll
    for (int i = 0; i < CG; ++i)
        #pragma unroll
        for (int r = 0; r < 3; ++r)
            xr[i][r] = *reinterpret_cast<const float4*>(xb + (long)i * cs + roff[r]);

    // fence: nothing below may be hoisted above, nothing above sunk below —
    // x loads stay issued (in flight) while softmax runs.
    __builtin_amdgcn_sched_barrier(0);

    // ---- softmax over the 9 taps for this thread's 4 pixels ----
    #pragma unroll
    for (int p = 0; p < 4; ++p) {
        float m = kv[0][p];
        #pragma unroll
        for (int j = 1; j < 9; ++j) m = fmaxf(m, kv[j][p]);
        float s = 0.f;
        #pragma unroll
        for (int j = 0; j < 9; ++j) { kv[j][p] = __expf(kv[j][p] - m); s += kv[j][p]; }
        const float inv = 1.0f / s;
        #pragma unroll
        for (int j = 0; j < 9; ++j) kv[j][p] *= inv;
    }

    // ---- conv on the preloaded rows; halo via cross-lane shuffle ----
    #pragma unroll
    for (int i = 0; i < CG; ++i) {
        float acc0 = 0.f, acc1 = 0.f, acc2 = 0.f, acc3 = 0.f;
        #pragma unroll
        for (int r = 0; r < 3; ++r) {
            const float4 v = xr[i][r];
            float lft = __shfl_up(v.w, 1);
            if (wq == 0)  lft = v.y;     // reflect x[-1] -> x[1]
            float rgt = __shfl_down(v.x, 1);
            if (wq == 63) rgt = v.z;     // reflect x[256] -> x[254]
            const float vals[6] = { lft, v.x, v.y, v.z, v.w, rgt };
            #pragma unroll
            for (int dx = 0; dx < 3; ++dx) {
                const int j = r * 3 + dx;
                acc0 = fmaf(kv[j][0], vals[0 + dx], acc0);
                acc1 = fmaf(kv[j][1], vals[1 + dx], acc1);
                acc2 = fmaf(kv[j][2], vals[2 + dx], acc2);
                acc3 = fmaf(kv[j][3], vals[3 + dx], acc3);
            }
        }
        vf4 o; o.x = acc0; o.y = acc1; o.z = acc2; o.w = acc3;
        __builtin_nontemporal_store(o, reinterpret_cast<vf4*>(ob + (long)i * cs + (long)h * WW + w0));
    }
}

extern "C" void kernel_launch(void* const* d_in, const int* in_sizes, int n_in,
                              void* d_out, int out_size, void* d_ws, size_t ws_size,
                              hipStream_t stream) {
    const float* x   = (const float*)d_in[0];
    const float* ker = (const float*)d_in[1];
    float* out = (float*)d_out;

    dim3 grid(HH / RPB, CHAN / CG, BATCH);  // (64, 16, 4)
    dim3 block(256);
    dynconv_kernel<<<grid, block, 0, stream>>>(x, ker, out);
}